// Round 5
// baseline (434.073 us; speedup 1.0000x reference)
//
#include <hip/hip_runtime.h>
#include <math.h>

#define MM 1024      // checks
#define NN 2048      // vars
#define BB 128       // batch
#define TT 5         // iterations
#define EE 6144      // edges

typedef __bf16 bf16x8 __attribute__((ext_vector_type(8)));
typedef __bf16 bf16x4 __attribute__((ext_vector_type(4)));
typedef short  s16x4  __attribute__((ext_vector_type(4)));
typedef float  f32x4  __attribute__((ext_vector_type(4)));
typedef unsigned int u32x4 __attribute__((ext_vector_type(4)));

// prepped weight sizes (bf16 elements)
#define CHK_W_ELEMS 22272   // 24 x32-frags (512) + 39 x16-frags (256)
#define CHK_L2_OFF  12288
#define VAR_W_ELEMS 7168    // 7 x32-frags + 14 x16-frags
#define VAR_L2_OFF  3584

// Abramowitz-Stegun 7.1.26 erf (|eps| < 1.5e-7)
__device__ __forceinline__ float gelu_fast(float x) {
    float xe = x * 0.70710678118654752f;
    float ax = fabsf(xe);
    float t  = __builtin_amdgcn_rcpf(1.0f + 0.3275911f * ax);
    float p  = t * (0.254829592f + t * (-0.284496736f + t * (1.421413741f +
               t * (-1.453152027f + t * 1.061405429f))));
    float er = 1.0f - p * __expf(-xe * xe);
    er = copysignf(er, xe);
    return 0.5f * x * (1.0f + er);
}

// 16x16x16 bf16 MFMA: B-operand layout == C/D layout of a prior MFMA ->
// register-chained layer2 (no LDS transpose on the critical path).
__device__ __forceinline__ f32x4 mfma16(bf16x4 a, bf16x4 b, f32x4 c) {
#if __has_builtin(__builtin_amdgcn_mfma_f32_16x16x16bf16_1k)
    return __builtin_amdgcn_mfma_f32_16x16x16bf16_1k(
        __builtin_bit_cast(s16x4, a), __builtin_bit_cast(s16x4, b), c, 0, 0, 0);
#else
    f32x4 d;
    asm volatile("v_mfma_f32_16x16x16_bf16 %0, %1, %2, %3\n\ts_nop 4"
                 : "=v"(d) : "v"(a), "v"(b), "v"(c));
    return d;
#endif
}

// wave-private LDS fence (DS ops in-order per wave)
__device__ __forceinline__ void wave_lds_fence() {
    asm volatile("s_waitcnt lgkmcnt(0)" ::: "memory");
}

// ---------------------------------------------------------------------------
// prep_fused r3: barrier-free wave-private packing. Pinned at ~2.9 TB/s
// (mixed R/W ceiling) across 4 structurally different implementations --
// kept as-is; no further prep work.
// ---------------------------------------------------------------------------
#define PREP_GRID (1024 + 2048 + 512 + 3072)

__global__ __launch_bounds__(256, 6)
void prep_fused(const float* __restrict__ cw1, const float* __restrict__ cb1,
                const float* __restrict__ cw2, const float* __restrict__ cb2,
                const float* __restrict__ vw1, const float* __restrict__ vb1,
                const float* __restrict__ vw2, const float* __restrict__ vb2,
                const int* __restrict__ synd, const float* __restrict__ prior,
                __bf16* __restrict__ wchk, __bf16* __restrict__ wvar,
                float* __restrict__ sgnT, __bf16* __restrict__ v2c)
{
    const int bid = blockIdx.x;
    const int tid = threadIdx.x;
    const int w = tid >> 6, l = tid & 63, q = l >> 4, c = l & 15;

    __shared__ __align__(16) float s[6656];   // 26 KB = 4 x 1664-float wave slices
    float* sw = s + w * 1664;                  // wave-private slice

    if (bid < 1024) {
        // ================= chk weight pack (one m) =================
        const int m = bid;
        const float* w1p = cw1 + (size_t)m * 9216;
        const float* w2p = cw2 + (size_t)m * 9216;
        __bf16* dst = wchk + (size_t)m * CHK_W_ELEMS;

        // ---- w1, col slice [48w, 48w+48), kt=0 (rows 0..31); pitch 50 ----
        #pragma unroll
        for (int i0 = 0; i0 < 6; ++i0) {
            int i = i0 * 64 + l;
            int r = i / 12, c4 = i % 12;
            float4 v = *(const float4*)(w1p + r * 192 + w * 48 + c4 * 4);
            *(float2*)(sw + r * 50 + c4 * 4)     = make_float2(v.x, v.y);
            *(float2*)(sw + r * 50 + c4 * 4 + 2) = make_float2(v.z, v.w);
        }
        wave_lds_fence();
        #pragma unroll
        for (int d = 0; d < 3; ++d) {
            int mt = 3 * w + d;
            bf16x8 v;
            #pragma unroll
            for (int j = 0; j < 8; ++j)
                v[j] = (__bf16)sw[(q * 8 + j) * 50 + d * 16 + c];
            *(bf16x8*)(dst + (mt * 2) * 512 + l * 8) = v;
        }
        wave_lds_fence();

        // ---- w1 kt=1 (rows 32..47 local 0..15, bias row 16) ----
        #pragma unroll
        for (int i0 = 0; i0 < 4; ++i0) {
            int i = i0 * 64 + l;
            if (i < 204) {
                int r = i / 12, c4 = i % 12;
                const float* src = (r < 16)
                    ? (w1p + (32 + r) * 192 + w * 48 + c4 * 4)
                    : (cb1 + (size_t)m * 192 + w * 48 + c4 * 4);
                float4 v = *(const float4*)src;
                *(float2*)(sw + r * 50 + c4 * 4)     = make_float2(v.x, v.y);
                *(float2*)(sw + r * 50 + c4 * 4 + 2) = make_float2(v.z, v.w);
            }
        }
        wave_lds_fence();
        #pragma unroll
        for (int d = 0; d < 3; ++d) {
            int mt = 3 * w + d;
            bf16x8 v;
            #pragma unroll
            for (int j = 0; j < 8; ++j) {
                int lr = q * 8 + j;                  // k = 32 + lr
                float wv = sw[lr * 50 + d * 16 + c]; // in-bounds garbage ok
                v[j] = (__bf16)((lr <= 16) ? wv : 0.0f);
            }
            *(bf16x8*)(dst + (mt * 2 + 1) * 512 + l * 8) = v;
        }
        wave_lds_fence();

        // ---- w2 tasks: t in 0..8 = (kb,mt) tiles; t=9 = ks12 bias frags ----
        for (int t = w; t < 10; t += 4) {
            if (t < 9) {
                const int kb = t / 3, mt = t - kb * 3;
                // stage rows [64kb, 64kb+64), cols [16mt, 16mt+16); pitch 20
                #pragma unroll
                for (int i0 = 0; i0 < 4; ++i0) {
                    int i = i0 * 64 + l;
                    int r = i >> 2, c4 = i & 3;
                    float4 v = *(const float4*)(w2p + (kb * 64 + r) * 48 + mt * 16 + c4 * 4);
                    *(float4*)(sw + r * 20 + c4 * 4) = v;
                }
                wave_lds_fence();
                #pragma unroll
                for (int kk = 0; kk < 4; ++kk) {
                    bf16x4 v;
                    #pragma unroll
                    for (int r = 0; r < 4; ++r)
                        v[r] = (__bf16)sw[(kk * 16 + q * 4 + r) * 20 + c];
                    *(bf16x4*)(dst + CHK_L2_OFF + ((kb * 4 + kk) * 3 + mt) * 256 + l * 4) = v;
                }
                wave_lds_fence();
            } else {
                // ks = 12: only k==192 (q==0, r==0) is the bias row
                #pragma unroll
                for (int mt = 0; mt < 3; ++mt) {
                    bf16x4 v;
                    #pragma unroll
                    for (int r = 0; r < 4; ++r) v[r] = (__bf16)0.0f;
                    if (q == 0) v[0] = (__bf16)cb2[(size_t)m * 48 + mt * 16 + c];
                    *(bf16x4*)(dst + CHK_L2_OFF + (36 + mt) * 256 + l * 4) = v;
                }
            }
        }
    } else if (bid < 3072) {
        // ================= var weight pack (one nv) =================
        const int nv = bid - 1024;
        const float* w1p = vw1 + (size_t)nv * 2500;
        const float* w2p = vw2 + (size_t)nv * 2500;
        __bf16* dst = wvar + (size_t)nv * VAR_W_ELEMS;

        if (w < 3) {
            #pragma unroll
            for (int i0 = 0; i0 < 4; ++i0) {
                int i = i0 * 64 + l;
                if (i < 208) {
                    int r = i >> 3, c4 = i & 7;
                    const float* src = (r < 25)
                        ? (w1p + r * 100 + w * 32 + c4 * 4)
                        : (vb1 + (size_t)nv * 100 + w * 32 + c4 * 4);
                    float4 v = *(const float4*)src;
                    *(float2*)(sw + r * 34 + c4 * 4)     = make_float2(v.x, v.y);
                    *(float2*)(sw + r * 34 + c4 * 4 + 2) = make_float2(v.z, v.w);
                }
            }
        } else {
            if (l < 26) {
                int r = l;
                const float* src = (r < 25) ? (w1p + r * 100 + 96)
                                            : (vb1 + (size_t)nv * 100 + 96);
                float4 v = *(const float4*)src;
                *(float2*)(sw + r * 34)     = make_float2(v.x, v.y);
                *(float2*)(sw + r * 34 + 2) = make_float2(v.z, v.w);
            }
        }
        wave_lds_fence();
        {
            const int nmt = (w < 3) ? 2 : 1;
            #pragma unroll
            for (int d = 0; d < 2; ++d) {
                if (d < nmt) {
                    const int mt = (w < 3) ? (2 * w + d) : 6;
                    const int h = mt * 16 + c;
                    bf16x8 v;
                    #pragma unroll
                    for (int j = 0; j < 8; ++j) {
                        int k = q * 8 + j;
                        float wv = sw[k * 34 + d * 16 + c];   // in-bounds garbage ok
                        v[j] = (__bf16)((h < 100 && k <= 25) ? wv : 0.0f);
                    }
                    *(bf16x8*)(dst + mt * 512 + l * 8) = v;
                }
            }
        }
        wave_lds_fence();

        if (w < 3) {
            #pragma unroll
            for (int i0 = 0; i0 < 4; ++i0) {
                int i = i0 * 64 + l;
                if (i < 200)
                    *(float4*)(sw + i * 4) = *(const float4*)(w2p + 800 * w + i * 4);
            }
        } else {
            if (l < 25) *(float4*)(sw + l * 4) = *(const float4*)(w2p + 2400 + l * 4);
            if (l < 25) sw[100 + l] = vb2[(size_t)nv * 25 + l];
        }
        wave_lds_fence();
        {
            const int nks = (w < 3) ? 2 : 1;
            #pragma unroll
            for (int kk = 0; kk < 2; ++kk) {
                if (kk < nks) {
                    const int ks = (w < 3) ? (2 * w + kk) : 6;
                    #pragma unroll
                    for (int mt = 0; mt < 2; ++mt) {
                        const int o = mt * 16 + c;
                        bf16x4 v;
                        #pragma unroll
                        for (int r = 0; r < 4; ++r) {
                            float x;
                            if (w < 3) {
                                int lk = kk * 16 + q * 4 + r;     // k=32w+lk <= 95 < 100
                                float wv = sw[lk * 25 + o];
                                x = (o < 25) ? wv : 0.0f;
                            } else {
                                int lk = q * 4 + r;               // k = 96+lk; lk==4 -> bias
                                float wv = sw[lk * 25 + o];
                                x = (o < 25 && lk <= 4) ? wv : 0.0f;
                            }
                            v[r] = (__bf16)x;
                        }
                        *(bf16x4*)(dst + VAR_L2_OFF + (ks * 2 + mt) * 256 + l * 4) = v;
                    }
                }
            }
        }
    } else if (bid < 3584) {
        // ---------------- syndrome sign transpose ----------------
        int idx = (bid - 3072) * 256 + tid;        // m*128 + b
        int m = idx >> 7, b = idx & 127;
        sgnT[idx] = (float)(1 - 2 * synd[(size_t)b * MM + m]);
    } else {
        // ---------------- v2c init ----------------
        int idx = (bid - 3584) * 256 + tid;
        int e = idx >> 7;
        bf16x8 v;
        #pragma unroll
        for (int j = 0; j < 8; ++j) v[j] = (__bf16)0.0f;
        v[0] = (__bf16)prior[e / 3];
        *(bf16x8*)(v2c + (size_t)idx * 8) = v;
    }
}

// ---------------------------------------------------------------------------
// Check MLP r5: NO LDS weight staging. Weight fragments are linear-per-lane
// in global memory (wp + frag_off + l*8) -> coalesced 16B/lane loads served
// by L1/L2/L3 (weight set is L3-resident after iter 1). This removes the
// stage phase, the vmcnt drain, and ALL block barriers; LDS drops to the
// 7.25 KB wave-private ytile, so all 4 blocks/CU are resident (zero tail)
// and 16 waves/CU of TLP hide cache latency behind MFMA+gelu.
// ---------------------------------------------------------------------------
#define CPITCH 58   // Y tile pitch (elements); 29c mod 32 spreads banks
__global__ __launch_bounds__(256, 4)
void chk_kernel(const __bf16* __restrict__ wchk,
                const float* __restrict__ sgnT,
                const int* __restrict__ v2c_gather,
                const __bf16* __restrict__ v2c, __bf16* __restrict__ c2v)
{
    const int m = blockIdx.x;
    const int tid = threadIdx.x;
    const int w = tid >> 6, l = tid & 63, q = l >> 4, c = l & 15;

    __shared__ __align__(16) __bf16 ytile[4 * 16 * CPITCH]; // 7.25 KB

    const __bf16* wp = wchk + (size_t)m * CHK_W_ELEMS;

    // edge ids first
    const int e0 = v2c_gather[m * 6 + q];
    const int e1 = (q < 2) ? v2c_gather[m * 6 + 4 + q] : 0;

    // prefetch B-frags + signs for both t2 halves (overlaps weight loads)
    bf16x8 bA[2], bB[2];
    float sg[2];
    #pragma unroll
    for (int t2 = 0; t2 < 2; ++t2) {
        const int bt = t2 * 64 + w * 16;
        bA[t2] = *(const bf16x8*)(v2c + ((size_t)e0 * BB + bt + c) * 8);
        bf16x8 bb;
        #pragma unroll
        for (int j = 0; j < 8; ++j) bb[j] = (__bf16)0.0f;
        if (q < 2)       bb = *(const bf16x8*)(v2c + ((size_t)e1 * BB + bt + c) * 8);
        else if (q == 2) bb[0] = (__bf16)1.0f;   // bias row k=48
        bB[t2] = bb;
        sg[t2] = sgnT[m * BB + bt + c];
    }

    __bf16* myy = ytile + w * 16 * CPITCH;   // [batch 16][out 48], wave-private

    #pragma unroll
    for (int t2 = 0; t2 < 2; ++t2) {
        const int bt = t2 * 64 + w * 16;

        // layer 1: 12 hidden tiles (x32), A-frags straight from global
        f32x4 acc[12];
        #pragma unroll
        for (int mt = 0; mt < 12; ++mt) {
            bf16x8 a0 = *(const bf16x8*)(wp + (mt * 2 + 0) * 512 + l * 8);
            bf16x8 a1 = *(const bf16x8*)(wp + (mt * 2 + 1) * 512 + l * 8);
            f32x4 z = {0.f, 0.f, 0.f, 0.f};
            z = __builtin_amdgcn_mfma_f32_16x16x32_bf16(a0, bA[t2], z, 0, 0, 0);
            z = __builtin_amdgcn_mfma_f32_16x16x32_bf16(a1, bB[t2], z, 0, 0, 0);
            acc[mt] = z;
        }

        // layer 2: 13 x16 k-steps, B-frag = gelu(acc) straight from registers
        f32x4 acc2[3];
        #pragma unroll
        for (int mt = 0; mt < 3; ++mt) acc2[mt] = (f32x4){0.f, 0.f, 0.f, 0.f};
        #pragma unroll
        for (int ks = 0; ks < 13; ++ks) {
            bf16x4 bf;
            if (ks < 12) {
                #pragma unroll
                for (int r = 0; r < 4; ++r) bf[r] = (__bf16)gelu_fast(acc[ks][r]);
            } else {
                #pragma unroll
                for (int r = 0; r < 4; ++r) bf[r] = (__bf16)0.0f;
                if (q == 0) bf[0] = (__bf16)1.0f;   // k=192 bias row
            }
            #pragma unroll
            for (int mt = 0; mt < 3; ++mt) {
                bf16x4 af = *(const bf16x4*)(wp + CHK_L2_OFF + (ks * 3 + mt) * 256 + l * 4);
                acc2[mt] = mfma16(af, bf, acc2[mt]);
            }
        }

        // epilogue: sign + transpose via wave-private LDS tile [b][o]
        #pragma unroll
        for (int mt = 0; mt < 3; ++mt)
            #pragma unroll
            for (int r = 0; r < 4; ++r)
                myy[c * CPITCH + mt * 16 + q * 4 + r] = (__bf16)(acc2[mt][r] * sg[t2]);
        wave_lds_fence();

        // coalesced 16B chunk stores: (slot s, row) -> c2v[e=m*6+s][bt+row][0..7]
        {
            int s = l >> 4, row = l & 15;
            u32x4 vv = *(const u32x4*)(myy + row * CPITCH + s * 8);
            *(u32x4*)(c2v + ((size_t)(m * 6 + s) * BB + bt + row) * 8) = vv;
            if (l < 32) {
                int s2 = 4 + (l >> 4), row2 = l & 15;
                u32x4 v2 = *(const u32x4*)(myy + row2 * CPITCH + s2 * 8);
                *(u32x4*)(c2v + ((size_t)(m * 6 + s2) * BB + bt + row2) * 8) = v2;
            }
        }
        wave_lds_fence();   // reads done before next-t2 tile writes
    }
}

// ---------------------------------------------------------------------------
// Variable MLP r5: same cache-served direct weight reads; 3.25 KB LDS only.
// ---------------------------------------------------------------------------
#define VPITCH 26
__global__ __launch_bounds__(256, 5)
void var_kernel(const __bf16* __restrict__ wvar,
                const int* __restrict__ c2v_gather, const float* __restrict__ prior,
                const __bf16* __restrict__ c2v, __bf16* __restrict__ v2c,
                float* __restrict__ llr_out, int last)
{
    const int nv = blockIdx.x;
    const int tid = threadIdx.x;
    const int w = tid >> 6, l = tid & 63, q = l >> 4, c = l & 15;

    __shared__ __align__(16) __bf16 ytile[4 * 16 * VPITCH]; // 3.25 KB

    const __bf16* wp = wvar + (size_t)nv * VAR_W_ELEMS;

    const int ep = (q < 3) ? c2v_gather[nv * 3 + q] : 0;
    const __bf16 prbf = (__bf16)prior[nv];

    // prefetch both t2 B-frags
    bf16x8 bp[2];
    #pragma unroll
    for (int t2 = 0; t2 < 2; ++t2) {
        const int bt = t2 * 64 + w * 16;
        bf16x8 bb;
        #pragma unroll
        for (int j = 0; j < 8; ++j) bb[j] = (__bf16)0.0f;
        if (q < 3) bb = *(const bf16x8*)(c2v + ((size_t)ep * BB + bt + c) * 8);
        else { bb[0] = prbf; bb[1] = (__bf16)1.0f; }   // k=24 prior, k=25 bias
        bp[t2] = bb;
    }

    __bf16* myy = ytile + w * 16 * VPITCH;   // [batch 16][out 24]

    #pragma unroll
    for (int t2 = 0; t2 < 2; ++t2) {
        const int bt = t2 * 64 + w * 16;
        const bf16x8 b0 = bp[t2];

        f32x4 acc[7];
        #pragma unroll
        for (int mt = 0; mt < 7; ++mt) {
            bf16x8 a0 = *(const bf16x8*)(wp + mt * 512 + l * 8);
            f32x4 z = {0.f, 0.f, 0.f, 0.f};
            acc[mt] = __builtin_amdgcn_mfma_f32_16x16x32_bf16(a0, b0, z, 0, 0, 0);
        }

        f32x4 acc2[2];
        acc2[0] = (f32x4){0.f, 0.f, 0.f, 0.f};
        acc2[1] = (f32x4){0.f, 0.f, 0.f, 0.f};
        #pragma unroll
        for (int ks = 0; ks < 7; ++ks) {
            bf16x4 bf;
            #pragma unroll
            for (int r = 0; r < 4; ++r) bf[r] = (__bf16)gelu_fast(acc[ks][r]);
            if (ks == 6 && q == 1) bf[0] = (__bf16)1.0f;   // k=100 bias row
            #pragma unroll
            for (int mt = 0; mt < 2; ++mt) {
                bf16x4 af = *(const bf16x4*)(wp + VAR_L2_OFF + (ks * 2 + mt) * 256 + l * 4);
                acc2[mt] = mfma16(af, bf, acc2[mt]);
            }
        }

        // epilogue: messages (o<24) via LDS tile; LLR (o=24) f32 direct
        #pragma unroll
        for (int r = 0; r < 4; ++r)
            myy[c * VPITCH + q * 4 + r] = (__bf16)acc2[0][r];
        if (q < 2)
            #pragma unroll
            for (int r = 0; r < 4; ++r)
                myy[c * VPITCH + 16 + q * 4 + r] = (__bf16)acc2[1][r];
        if (q == 2) llr_out[(size_t)(bt + c) * NN + nv] = acc2[1][0];
        wave_lds_fence();

        if (!last && l < 48) {
            int s = l >> 4, row = l & 15;
            u32x4 vv = *(const u32x4*)(myy + row * VPITCH + s * 8);
            *(u32x4*)(v2c + ((size_t)(nv * 3 + s) * BB + bt + row) * 8) = vv;
        }
        wave_lds_fence();
    }
}

extern "C" void kernel_launch(void* const* d_in, const int* in_sizes, int n_in,
                              void* d_out, int out_size, void* d_ws, size_t ws_size,
                              hipStream_t stream) {
    const int*   syndromes = (const int*)  d_in[0];
    const float* prior_llr = (const float*)d_in[1];
    const float* chk_w1    = (const float*)d_in[2];
    const float* chk_b1    = (const float*)d_in[3];
    const float* chk_w2    = (const float*)d_in[4];
    const float* chk_b2    = (const float*)d_in[5];
    const float* var_w1    = (const float*)d_in[6];
    const float* var_b1    = (const float*)d_in[7];
    const float* var_w2    = (const float*)d_in[8];
    const float* var_b2    = (const float*)d_in[9];
    const int*   c2v_g     = (const int*)  d_in[11];
    const int*   v2c_g     = (const int*)  d_in[12];

    float* out = (float*)d_out;

    __bf16* v2c  = (__bf16*)d_ws;                           // 12.6 MB
    __bf16* c2v  = v2c + (size_t)EE * BB * 8;               // 12.6 MB
    __bf16* wchk = c2v + (size_t)EE * BB * 8;               // 45.6 MB
    __bf16* wvar = wchk + (size_t)MM * CHK_W_ELEMS;         // 29.4 MB
    float*  sgnT = (float*)(wvar + (size_t)NN * VAR_W_ELEMS); // 512 KB

    prep_fused<<<PREP_GRID, 256, 0, stream>>>(chk_w1, chk_b1, chk_w2, chk_b2,
                                              var_w1, var_b1, var_w2, var_b2,
                                              syndromes, prior_llr,
                                              wchk, wvar, sgnT, v2c);

    for (int t = 0; t < TT; ++t) {
        chk_kernel<<<MM, 256, 0, stream>>>(wchk, sgnT, v2c_g, v2c, c2v);
        var_kernel<<<NN, 256, 0, stream>>>(wvar, c2v_g, prior_llr, c2v, v2c,
                                           out + (size_t)t * BB * NN,
                                           (t == TT - 1) ? 1 : 0);
    }
}

// Round 6
// 394.856 us; speedup vs baseline: 1.0993x; 1.0993x over previous
//
#include <hip/hip_runtime.h>
#include <math.h>

#define MM 1024      // checks
#define NN 2048      // vars
#define BB 128       // batch
#define TT 5         // iterations
#define EE 6144      // edges

typedef __bf16 bf16x8 __attribute__((ext_vector_type(8)));
typedef __bf16 bf16x4 __attribute__((ext_vector_type(4)));
typedef short  s16x4  __attribute__((ext_vector_type(4)));
typedef float  f32x4  __attribute__((ext_vector_type(4)));
typedef unsigned int u32x4 __attribute__((ext_vector_type(4)));

typedef const __attribute__((address_space(1))) void* gas_p;
typedef __attribute__((address_space(3))) void* las_p;

// prepped weight sizes (bf16 elements)
// chk L2 layout (r6): per mt (3): 6 interleaved ks-pairs (512 el) + ks12 (256 el) = 3328 el
#define CHK_W_ELEMS 22272   // 24 x32-frags (512) + 3*3328 L2
#define CHK_L2_OFF  12288
// var L2 layout (r6): per mt (2): 3 interleaved ks-pairs (512) + ks6 (256) = 1792 el
#define VAR_W_ELEMS 7168
#define VAR_L2_OFF  3584

// Abramowitz-Stegun 7.1.26 erf (|eps| < 1.5e-7)
__device__ __forceinline__ float gelu_fast(float x) {
    float xe = x * 0.70710678118654752f;
    float ax = fabsf(xe);
    float t  = __builtin_amdgcn_rcpf(1.0f + 0.3275911f * ax);
    float p  = t * (0.254829592f + t * (-0.284496736f + t * (1.421413741f +
               t * (-1.453152027f + t * 1.061405429f))));
    float er = 1.0f - p * __expf(-xe * xe);
    er = copysignf(er, xe);
    return 0.5f * x * (1.0f + er);
}

// 16x16x16 bf16 MFMA: B-operand layout == C/D layout of a prior MFMA ->
// register-chained layer2 (no LDS transpose on the critical path).
__device__ __forceinline__ f32x4 mfma16(bf16x4 a, bf16x4 b, f32x4 c) {
#if __has_builtin(__builtin_amdgcn_mfma_f32_16x16x16bf16_1k)
    return __builtin_amdgcn_mfma_f32_16x16x16bf16_1k(
        __builtin_bit_cast(s16x4, a), __builtin_bit_cast(s16x4, b), c, 0, 0, 0);
#else
    f32x4 d;
    asm volatile("v_mfma_f32_16x16x16_bf16 %0, %1, %2, %3\n\ts_nop 4"
                 : "=v"(d) : "v"(a), "v"(b), "v"(c));
    return d;
#endif
}

// wave-private LDS fence (DS ops in-order per wave)
__device__ __forceinline__ void wave_lds_fence() {
    asm volatile("s_waitcnt lgkmcnt(0)" ::: "memory");
}

// ---------------------------------------------------------------------------
// prep r6: split into prep_chk + prep_other so each dispatch is shorter than
// chk_kernel -> loop kernels surface in rocprof top-5 (instrumentation).
// Same barrier-free wave-private packing as r3 (pinned at mixed-R/W ceiling).
// L2-fragment emission now writes lane-interleaved ks-PAIRS so the loop
// kernels read layer-2 weights as ds_read_b128 (half the DS ops).
// ---------------------------------------------------------------------------
__global__ __launch_bounds__(256, 6)
void prep_chk(const float* __restrict__ cw1, const float* __restrict__ cb1,
              const float* __restrict__ cw2, const float* __restrict__ cb2,
              __bf16* __restrict__ wchk)
{
    const int tid = threadIdx.x;
    const int w = tid >> 6, l = tid & 63, q = l >> 4, c = l & 15;

    __shared__ __align__(16) float s[6656];   // 26 KB = 4 x 1664-float wave slices
    float* sw = s + w * 1664;                  // wave-private slice

    const int m = blockIdx.x;
    const float* w1p = cw1 + (size_t)m * 9216;
    const float* w2p = cw2 + (size_t)m * 9216;
    __bf16* dst = wchk + (size_t)m * CHK_W_ELEMS;

    // ---- w1, col slice [48w, 48w+48), kt=0 (rows 0..31); pitch 50 ----
    #pragma unroll
    for (int i0 = 0; i0 < 6; ++i0) {
        int i = i0 * 64 + l;
        int r = i / 12, c4 = i % 12;
        float4 v = *(const float4*)(w1p + r * 192 + w * 48 + c4 * 4);
        *(float2*)(sw + r * 50 + c4 * 4)     = make_float2(v.x, v.y);
        *(float2*)(sw + r * 50 + c4 * 4 + 2) = make_float2(v.z, v.w);
    }
    wave_lds_fence();
    #pragma unroll
    for (int d = 0; d < 3; ++d) {
        int mt = 3 * w + d;
        bf16x8 v;
        #pragma unroll
        for (int j = 0; j < 8; ++j)
            v[j] = (__bf16)sw[(q * 8 + j) * 50 + d * 16 + c];
        *(bf16x8*)(dst + (mt * 2) * 512 + l * 8) = v;
    }
    wave_lds_fence();

    // ---- w1 kt=1 (rows 32..47 local 0..15, bias row 16) ----
    #pragma unroll
    for (int i0 = 0; i0 < 4; ++i0) {
        int i = i0 * 64 + l;
        if (i < 204) {
            int r = i / 12, c4 = i % 12;
            const float* src = (r < 16)
                ? (w1p + (32 + r) * 192 + w * 48 + c4 * 4)
                : (cb1 + (size_t)m * 192 + w * 48 + c4 * 4);
            float4 v = *(const float4*)src;
            *(float2*)(sw + r * 50 + c4 * 4)     = make_float2(v.x, v.y);
            *(float2*)(sw + r * 50 + c4 * 4 + 2) = make_float2(v.z, v.w);
        }
    }
    wave_lds_fence();
    #pragma unroll
    for (int d = 0; d < 3; ++d) {
        int mt = 3 * w + d;
        bf16x8 v;
        #pragma unroll
        for (int j = 0; j < 8; ++j) {
            int lr = q * 8 + j;                  // k = 32 + lr
            float wv = sw[lr * 50 + d * 16 + c]; // in-bounds garbage ok
            v[j] = (__bf16)((lr <= 16) ? wv : 0.0f);
        }
        *(bf16x8*)(dst + (mt * 2 + 1) * 512 + l * 8) = v;
    }
    wave_lds_fence();

    // ---- w2 tasks: t in 0..8 = (kb,mt) tiles; t=9 = ks12 bias frags ----
    // emission: pair-interleaved — ks pair kp at mt*3328 + kp*512, lane l
    // holds [ksA(l) : ksB(l)] so the consumer reads one b128 per pair.
    for (int t = w; t < 10; t += 4) {
        if (t < 9) {
            const int kb = t / 3, mt = t - kb * 3;
            // stage rows [64kb, 64kb+64), cols [16mt, 16mt+16); pitch 20
            #pragma unroll
            for (int i0 = 0; i0 < 4; ++i0) {
                int i = i0 * 64 + l;
                int r = i >> 2, c4 = i & 3;
                float4 v = *(const float4*)(w2p + (kb * 64 + r) * 48 + mt * 16 + c4 * 4);
                *(float4*)(sw + r * 20 + c4 * 4) = v;
            }
            wave_lds_fence();
            #pragma unroll
            for (int kk = 0; kk < 4; ++kk) {
                const int ks = kb * 4 + kk;
                const int kp = ks >> 1, half = ks & 1;
                bf16x4 v;
                #pragma unroll
                for (int r = 0; r < 4; ++r)
                    v[r] = (__bf16)sw[(kk * 16 + q * 4 + r) * 20 + c];
                *(bf16x4*)(dst + CHK_L2_OFF + mt * 3328 + kp * 512 + l * 8 + half * 4) = v;
            }
            wave_lds_fence();
        } else {
            // ks = 12: only k==192 (q==0, r==0) is the bias row
            #pragma unroll
            for (int mt = 0; mt < 3; ++mt) {
                bf16x4 v;
                #pragma unroll
                for (int r = 0; r < 4; ++r) v[r] = (__bf16)0.0f;
                if (q == 0) v[0] = (__bf16)cb2[(size_t)m * 48 + mt * 16 + c];
                *(bf16x4*)(dst + CHK_L2_OFF + mt * 3328 + 3072 + l * 4) = v;
            }
        }
    }
}

#define PREP_OTHER_GRID (2048 + 512 + 3072)

__global__ __launch_bounds__(256, 6)
void prep_other(const float* __restrict__ vw1, const float* __restrict__ vb1,
                const float* __restrict__ vw2, const float* __restrict__ vb2,
                const int* __restrict__ synd, const float* __restrict__ prior,
                __bf16* __restrict__ wvar, float* __restrict__ sgnT,
                __bf16* __restrict__ v2c)
{
    const int bid = blockIdx.x;
    const int tid = threadIdx.x;
    const int w = tid >> 6, l = tid & 63, q = l >> 4, c = l & 15;

    __shared__ __align__(16) float s[6656];
    float* sw = s + w * 1664;

    if (bid < 2048) {
        // ================= var weight pack (one nv) =================
        const int nv = bid;
        const float* w1p = vw1 + (size_t)nv * 2500;
        const float* w2p = vw2 + (size_t)nv * 2500;
        __bf16* dst = wvar + (size_t)nv * VAR_W_ELEMS;

        if (w < 3) {
            #pragma unroll
            for (int i0 = 0; i0 < 4; ++i0) {
                int i = i0 * 64 + l;
                if (i < 208) {
                    int r = i >> 3, c4 = i & 7;
                    const float* src = (r < 25)
                        ? (w1p + r * 100 + w * 32 + c4 * 4)
                        : (vb1 + (size_t)nv * 100 + w * 32 + c4 * 4);
                    float4 v = *(const float4*)src;
                    *(float2*)(sw + r * 34 + c4 * 4)     = make_float2(v.x, v.y);
                    *(float2*)(sw + r * 34 + c4 * 4 + 2) = make_float2(v.z, v.w);
                }
            }
        } else {
            if (l < 26) {
                int r = l;
                const float* src = (r < 25) ? (w1p + r * 100 + 96)
                                            : (vb1 + (size_t)nv * 100 + 96);
                float4 v = *(const float4*)src;
                *(float2*)(sw + r * 34)     = make_float2(v.x, v.y);
                *(float2*)(sw + r * 34 + 2) = make_float2(v.z, v.w);
            }
        }
        wave_lds_fence();
        {
            const int nmt = (w < 3) ? 2 : 1;
            #pragma unroll
            for (int d = 0; d < 2; ++d) {
                if (d < nmt) {
                    const int mt = (w < 3) ? (2 * w + d) : 6;
                    const int h = mt * 16 + c;
                    bf16x8 v;
                    #pragma unroll
                    for (int j = 0; j < 8; ++j) {
                        int k = q * 8 + j;
                        float wv = sw[k * 34 + d * 16 + c];   // in-bounds garbage ok
                        v[j] = (__bf16)((h < 100 && k <= 25) ? wv : 0.0f);
                    }
                    *(bf16x8*)(dst + mt * 512 + l * 8) = v;
                }
            }
        }
        wave_lds_fence();

        if (w < 3) {
            #pragma unroll
            for (int i0 = 0; i0 < 4; ++i0) {
                int i = i0 * 64 + l;
                if (i < 200)
                    *(float4*)(sw + i * 4) = *(const float4*)(w2p + 800 * w + i * 4);
            }
        } else {
            if (l < 25) *(float4*)(sw + l * 4) = *(const float4*)(w2p + 2400 + l * 4);
            if (l < 25) sw[100 + l] = vb2[(size_t)nv * 25 + l];
        }
        wave_lds_fence();
        {
            // wave w<3 emits ks pair kp=w (ks=2w, 2w+1), interleaved; w3 emits ks=6
            const int nks = (w < 3) ? 2 : 1;
            #pragma unroll
            for (int kk = 0; kk < 2; ++kk) {
                if (kk < nks) {
                    #pragma unroll
                    for (int mt = 0; mt < 2; ++mt) {
                        const int o = mt * 16 + c;
                        bf16x4 v;
                        #pragma unroll
                        for (int r = 0; r < 4; ++r) {
                            float x;
                            if (w < 3) {
                                int lk = kk * 16 + q * 4 + r;     // k=32w+lk <= 95 < 100
                                float wv = sw[lk * 25 + o];
                                x = (o < 25) ? wv : 0.0f;
                            } else {
                                int lk = q * 4 + r;               // k = 96+lk; lk==4 -> bias
                                float wv = sw[lk * 25 + o];
                                x = (o < 25 && lk <= 4) ? wv : 0.0f;
                            }
                            v[r] = (__bf16)x;
                        }
                        if (w < 3)
                            *(bf16x4*)(dst + VAR_L2_OFF + mt * 1792 + w * 512 + l * 8 + kk * 4) = v;
                        else
                            *(bf16x4*)(dst + VAR_L2_OFF + mt * 1792 + 1536 + l * 4) = v;
                    }
                }
            }
        }
    } else if (bid < 2560) {
        // ---------------- syndrome sign transpose ----------------
        int idx = (bid - 2048) * 256 + tid;        // m*128 + b
        int m = idx >> 7, b = idx & 127;
        sgnT[idx] = (float)(1 - 2 * synd[(size_t)b * MM + m]);
    } else {
        // ---------------- v2c init ----------------
        int idx = (bid - 2560) * 256 + tid;
        int e = idx >> 7;
        bf16x8 v;
        #pragma unroll
        for (int j = 0; j < 8; ++j) v[j] = (__bf16)0.0f;
        v[0] = (__bf16)prior[e / 3];
        *(bf16x8*)(v2c + (size_t)idx * 8) = v;
    }
}

// ---------------------------------------------------------------------------
// chk layer helpers
// ---------------------------------------------------------------------------
__device__ __forceinline__ void chk_layer1(const __bf16* wlds, int l,
                                           bf16x8 b0, bf16x8 b1, f32x4* acc)
{
    #pragma unroll
    for (int mt = 0; mt < 12; ++mt) {
        bf16x8 a0 = *(const bf16x8*)(wlds + (mt * 2 + 0) * 512 + l * 8);
        bf16x8 a1 = *(const bf16x8*)(wlds + (mt * 2 + 1) * 512 + l * 8);
        f32x4 z = {0.f, 0.f, 0.f, 0.f};
        z = __builtin_amdgcn_mfma_f32_16x16x32_bf16(a0, b0, z, 0, 0, 0);
        z = __builtin_amdgcn_mfma_f32_16x16x32_bf16(a1, b1, z, 0, 0, 0);
        acc[mt] = z;
    }
}

// layer 2 with pair-interleaved frags: one ds_read_b128 per (mt, ks-pair)
// = 18 b128 + 3 b64 reads (was 39 b64). Accumulation order per acc2[mt]
// is still ks ascending -> bit-identical results.
__device__ __forceinline__ void chk_layer2(const __bf16* wlds, int l, int q,
                                           const f32x4* acc, f32x4* acc2)
{
    #pragma unroll
    for (int mt = 0; mt < 3; ++mt) acc2[mt] = (f32x4){0.f, 0.f, 0.f, 0.f};
    #pragma unroll
    for (int kp = 0; kp < 6; ++kp) {
        bf16x4 bf0, bf1;
        #pragma unroll
        for (int r = 0; r < 4; ++r) bf0[r] = (__bf16)gelu_fast(acc[2 * kp][r]);
        #pragma unroll
        for (int r = 0; r < 4; ++r) bf1[r] = (__bf16)gelu_fast(acc[2 * kp + 1][r]);
        #pragma unroll
        for (int mt = 0; mt < 3; ++mt) {
            bf16x8 a8 = *(const bf16x8*)(wlds + CHK_L2_OFF + mt * 3328 + kp * 512 + l * 8);
            bf16x4 alo = {a8[0], a8[1], a8[2], a8[3]};
            bf16x4 ahi = {a8[4], a8[5], a8[6], a8[7]};
            acc2[mt] = mfma16(alo, bf0, acc2[mt]);
            acc2[mt] = mfma16(ahi, bf1, acc2[mt]);
        }
    }
    // ks = 12: bias row (k=192)
    bf16x4 bfb;
    #pragma unroll
    for (int r = 0; r < 4; ++r) bfb[r] = (__bf16)0.0f;
    if (q == 0) bfb[0] = (__bf16)1.0f;
    #pragma unroll
    for (int mt = 0; mt < 3; ++mt) {
        bf16x4 af = *(const bf16x4*)(wlds + CHK_L2_OFF + mt * 3328 + 3072 + l * 4);
        acc2[mt] = mfma16(af, bfb, acc2[mt]);
    }
}

// ---------------------------------------------------------------------------
// Check MLP r6 = r4 structure (best known): gload_lds two-phase staging,
// b-frag/sign prefetch, vmcnt(5) releases layer1 while layer2 streams in.
// ---------------------------------------------------------------------------
#define CPITCH 58   // Y tile pitch (elements); 29c mod 32 spreads banks
__global__ __launch_bounds__(256, 3)
void chk_kernel(const __bf16* __restrict__ wchk,
                const float* __restrict__ sgnT,
                const int* __restrict__ v2c_gather,
                const __bf16* __restrict__ v2c, __bf16* __restrict__ c2v)
{
    const int m = blockIdx.x;
    const int tid = threadIdx.x;
    const int w = tid >> 6, l = tid & 63, q = l >> 4, c = l & 15;

    __shared__ __align__(16) __bf16 wlds[CHK_W_ELEMS];      // 43.5 KB
    __shared__ __align__(16) __bf16 ytile[4 * 16 * CPITCH]; // 7.25 KB

    // edge ids first
    const int e0 = v2c_gather[m * 6 + q];
    const int e1 = (q < 2) ? v2c_gather[m * 6 + 4 + q] : 0;

    // prefetch B-frags + signs for both t2 halves
    bf16x8 bA[2], bB[2];
    float sg[2];
    #pragma unroll
    for (int t2 = 0; t2 < 2; ++t2) {
        const int bt = t2 * 64 + w * 16;
        bA[t2] = *(const bf16x8*)(v2c + ((size_t)e0 * BB + bt + c) * 8);
        bf16x8 bb;
        #pragma unroll
        for (int j = 0; j < 8; ++j) bb[j] = (__bf16)0.0f;
        if (q < 2)       bb = *(const bf16x8*)(v2c + ((size_t)e1 * BB + bt + c) * 8);
        else if (q == 2) bb[0] = (__bf16)1.0f;   // bias row k=48
        bB[t2] = bb;
        sg[t2] = sgnT[m * BB + bt + c];
    }

    // stage weights: 11 gload_lds rounds of 4KB (last partial: 224 chunks)
    {
        const __bf16* src = wchk + (size_t)m * CHK_W_ELEMS;
        #pragma unroll
        for (int r = 0; r < 10; ++r)
            __builtin_amdgcn_global_load_lds(
                (gas_p)(src + (r * 256 + tid) * 8),
                (las_p)(wlds + (r * 256 + tid) * 8), 16, 0, 0);
        if (tid < 224)
            __builtin_amdgcn_global_load_lds(
                (gas_p)(src + (2560 + tid) * 8),
                (las_p)(wlds + (2560 + tid) * 8), 16, 0, 0);
    }
    __builtin_amdgcn_sched_barrier(0);
    asm volatile("s_waitcnt vmcnt(5)" ::: "memory");   // L1 rounds 0-5 landed
    __syncthreads();

    __bf16* myy = ytile + w * 16 * CPITCH;   // [batch 16][out 48], wave-private

    // ---- t2=0 layer1 (only L1 region) while L2 weights stream in ----
    f32x4 acc[12];
    chk_layer1(wlds, l, bA[0], bB[0], acc);

    __builtin_amdgcn_sched_barrier(0);
    asm volatile("s_waitcnt vmcnt(0)" ::: "memory");   // L2 rounds landed
    __syncthreads();

    #pragma unroll
    for (int t2 = 0; t2 < 2; ++t2) {
        if (t2 == 1) chk_layer1(wlds, l, bA[1], bB[1], acc);
        const int bt = t2 * 64 + w * 16;

        f32x4 acc2[3];
        chk_layer2(wlds, l, q, acc, acc2);

        // epilogue: sign + transpose via wave-private LDS tile [b][o]
        #pragma unroll
        for (int mt = 0; mt < 3; ++mt)
            #pragma unroll
            for (int r = 0; r < 4; ++r)
                myy[c * CPITCH + mt * 16 + q * 4 + r] = (__bf16)(acc2[mt][r] * sg[t2]);
        wave_lds_fence();

        // coalesced 16B chunk stores: (slot s, row) -> c2v[e=m*6+s][bt+row][0..7]
        {
            int s = l >> 4, row = l & 15;
            u32x4 vv = *(const u32x4*)(myy + row * CPITCH + s * 8);
            *(u32x4*)(c2v + ((size_t)(m * 6 + s) * BB + bt + row) * 8) = vv;
            if (l < 32) {
                int s2 = 4 + (l >> 4), row2 = l & 15;
                u32x4 v2 = *(const u32x4*)(myy + row2 * CPITCH + s2 * 8);
                *(u32x4*)(c2v + ((size_t)(m * 6 + s2) * BB + bt + row2) * 8) = v2;
            }
        }
        wave_lds_fence();   // reads done before next-t2 tile writes
    }
}

// ---------------------------------------------------------------------------
// Variable MLP r6 = r4 structure + paired layer-2 reads.
// ---------------------------------------------------------------------------
#define VPITCH 26
__global__ __launch_bounds__(256, 5)
void var_kernel(const __bf16* __restrict__ wvar,
                const int* __restrict__ c2v_gather, const float* __restrict__ prior,
                const __bf16* __restrict__ c2v, __bf16* __restrict__ v2c,
                float* __restrict__ llr_out, int last)
{
    const int nv = blockIdx.x;
    const int tid = threadIdx.x;
    const int w = tid >> 6, l = tid & 63, q = l >> 4, c = l & 15;

    __shared__ __align__(16) __bf16 wlds[VAR_W_ELEMS];      // 14.3 KB
    __shared__ __align__(16) __bf16 ytile[4 * 16 * VPITCH]; // 3.25 KB

    const int ep = (q < 3) ? c2v_gather[nv * 3 + q] : 0;
    const __bf16 prbf = (__bf16)prior[nv];

    // prefetch both t2 B-frags
    bf16x8 bp[2];
    #pragma unroll
    for (int t2 = 0; t2 < 2; ++t2) {
        const int bt = t2 * 64 + w * 16;
        bf16x8 bb;
        #pragma unroll
        for (int j = 0; j < 8; ++j) bb[j] = (__bf16)0.0f;
        if (q < 3) bb = *(const bf16x8*)(c2v + ((size_t)ep * BB + bt + c) * 8);
        else { bb[0] = prbf; bb[1] = (__bf16)1.0f; }   // k=24 prior, k=25 bias
        bp[t2] = bb;
    }

    // stage weights: 3 full rounds + 1 partial (128 chunks)
    {
        const __bf16* src = wvar + (size_t)nv * VAR_W_ELEMS;
        #pragma unroll
        for (int r = 0; r < 3; ++r)
            __builtin_amdgcn_global_load_lds(
                (gas_p)(src + (r * 256 + tid) * 8),
                (las_p)(wlds + (r * 256 + tid) * 8), 16, 0, 0);
        if (tid < 128)
            __builtin_amdgcn_global_load_lds(
                (gas_p)(src + (768 + tid) * 8),
                (las_p)(wlds + (768 + tid) * 8), 16, 0, 0);
    }
    __builtin_amdgcn_sched_barrier(0);
    asm volatile("s_waitcnt vmcnt(0)" ::: "memory");
    __syncthreads();

    __bf16* myy = ytile + w * 16 * VPITCH;   // [batch 16][out 24]

    #pragma unroll
    for (int t2 = 0; t2 < 2; ++t2) {
        const int bt = t2 * 64 + w * 16;
        const bf16x8 b0 = bp[t2];

        f32x4 acc[7];
        #pragma unroll
        for (int mt = 0; mt < 7; ++mt) {
            bf16x8 a0 = *(const bf16x8*)(wlds + mt * 512 + l * 8);
            f32x4 z = {0.f, 0.f, 0.f, 0.f};
            acc[mt] = __builtin_amdgcn_mfma_f32_16x16x32_bf16(a0, b0, z, 0, 0, 0);
        }

        f32x4 acc2[2];
        acc2[0] = (f32x4){0.f, 0.f, 0.f, 0.f};
        acc2[1] = (f32x4){0.f, 0.f, 0.f, 0.f};
        #pragma unroll
        for (int kp = 0; kp < 3; ++kp) {
            bf16x4 bf0, bf1;
            #pragma unroll
            for (int r = 0; r < 4; ++r) bf0[r] = (__bf16)gelu_fast(acc[2 * kp][r]);
            #pragma unroll
            for (int r = 0; r < 4; ++r) bf1[r] = (__bf16)gelu_fast(acc[2 * kp + 1][r]);
            #pragma unroll
            for (int mt = 0; mt < 2; ++mt) {
                bf16x8 a8 = *(const bf16x8*)(wlds + VAR_L2_OFF + mt * 1792 + kp * 512 + l * 8);
                bf16x4 alo = {a8[0], a8[1], a8[2], a8[3]};
                bf16x4 ahi = {a8[4], a8[5], a8[6], a8[7]};
                acc2[mt] = mfma16(alo, bf0, acc2[mt]);
                acc2[mt] = mfma16(ahi, bf1, acc2[mt]);
            }
        }
        {
            // ks = 6 (+ bias row k=100 at q==1,r==0)
            bf16x4 bf6;
            #pragma unroll
            for (int r = 0; r < 4; ++r) bf6[r] = (__bf16)gelu_fast(acc[6][r]);
            if (q == 1) bf6[0] = (__bf16)1.0f;
            #pragma unroll
            for (int mt = 0; mt < 2; ++mt) {
                bf16x4 af = *(const bf16x4*)(wlds + VAR_L2_OFF + mt * 1792 + 1536 + l * 4);
                acc2[mt] = mfma16(af, bf6, acc2[mt]);
            }
        }

        // epilogue: messages (o<24) via LDS tile; LLR (o=24) f32 direct
        #pragma unroll
        for (int r = 0; r < 4; ++r)
            myy[c * VPITCH + q * 4 + r] = (__bf16)acc2[0][r];
        if (q < 2)
            #pragma unroll
            for (int r = 0; r < 4; ++r)
                myy[c * VPITCH + 16 + q * 4 + r] = (__bf16)acc2[1][r];
        if (q == 2) llr_out[(size_t)(bt + c) * NN + nv] = acc2[1][0];
        wave_lds_fence();

        if (!last && l < 48) {
            int s = l >> 4, row = l & 15;
            u32x4 vv = *(const u32x4*)(myy + row * VPITCH + s * 8);
            *(u32x4*)(v2c + ((size_t)(nv * 3 + s) * BB + bt + row) * 8) = vv;
        }
        wave_lds_fence();
    }
}

extern "C" void kernel_launch(void* const* d_in, const int* in_sizes, int n_in,
                              void* d_out, int out_size, void* d_ws, size_t ws_size,
                              hipStream_t stream) {
    const int*   syndromes = (const int*)  d_in[0];
    const float* prior_llr = (const float*)d_in[1];
    const float* chk_w1    = (const float*)d_in[2];
    const float* chk_b1    = (const float*)d_in[3];
    const float* chk_w2    = (const float*)d_in[4];
    const float* chk_b2    = (const float*)d_in[5];
    const float* var_w1    = (const float*)d_in[6];
    const float* var_b1    = (const float*)d_in[7];
    const float* var_w2    = (const float*)d_in[8];
    const float* var_b2    = (const float*)d_in[9];
    const int*   c2v_g     = (const int*)  d_in[11];
    const int*   v2c_g     = (const int*)  d_in[12];

    float* out = (float*)d_out;

    __bf16* v2c  = (__bf16*)d_ws;                           // 12.6 MB
    __bf16* c2v  = v2c + (size_t)EE * BB * 8;               // 12.6 MB
    __bf16* wchk = c2v + (size_t)EE * BB * 8;               // 45.6 MB
    __bf16* wvar = wchk + (size_t)MM * CHK_W_ELEMS;         // 29.4 MB
    float*  sgnT = (float*)(wvar + (size_t)NN * VAR_W_ELEMS); // 512 KB

    prep_chk<<<MM, 256, 0, stream>>>(chk_w1, chk_b1, chk_w2, chk_b2, wchk);
    prep_other<<<PREP_OTHER_GRID, 256, 0, stream>>>(var_w1, var_b1, var_w2, var_b2,
                                                    syndromes, prior_llr,
                                                    wvar, sgnT, v2c);

    for (int t = 0; t < TT; ++t) {
        chk_kernel<<<MM, 256, 0, stream>>>(wchk, sgnT, v2c_g, v2c, c2v);
        var_kernel<<<NN, 256, 0, stream>>>(wvar, c2v_g, prior_llr, c2v, v2c,
                                           out + (size_t)t * BB * NN,
                                           (t == TT - 1) ? 1 : 0);
    }
}